// Round 1
// 77.774 us; speedup vs baseline: 1.0300x; 1.0300x over previous
//
#include <hip/hip_runtime.h>

// ANI feature kernel, molecule-tiled: grid=1536 blocks (6 blocks per molecule),
// block=256 (4 waves), each wave computes ONE center atom (1536*4 = 6144 rows).
// vs previous version (512 blocks, 3 centers/wave serial): 3x more blocks ->
// 6 blocks/CU dispatchable (~4 resident, 4 waves/SIMD vs 2) and 3x shorter
// per-wave dependent chain. Block stages the molecule's 24x24 distance matrix
// + rcp + cutoffs in LDS ONCE (law of cosines kills the need for rij vectors).
// Fast path: factorized k-grid term(k)=ff2*P_a*G_z (a=k>>3, z=k&7), 32
// accumulators/lane, shfl butterfly. Generic fallback per center if parameter
// structure differs.

constexpr int CB = 256;   // batch (molecules)
constexpr int CN = 24;    // atoms
constexpr int CKR = 16;
constexpr int CKA = 32;
constexpr int NN = 23;    // neighbors per center
constexpr int NP = 253;   // unordered neighbor pairs
constexpr int KOUT = CKR + CKA;  // 48
constexpr int LDM = 25;   // LDS leading dim for 24x24 (stride pad)
#define LOG2E 1.44269504088896340736f

struct PairTab { unsigned char pa[256]; unsigned char pb[256]; };
static constexpr PairTab make_pairs() {
    PairTab t{};
    int p = 0;
    for (int i = 0; i < NN; ++i)
        for (int j = i + 1; j < NN; ++j) {
            t.pa[p] = (unsigned char)i; t.pb[p] = (unsigned char)j; ++p;
        }
    for (; p < 256; ++p) { t.pa[p] = 0; t.pb[p] = 0; }
    return t;
}
__constant__ PairTab cPairs = make_pairs();

template<int MASK, int BIT, int HALF>
__device__ inline void red_level(float* acc, int lane) {
    const bool hi = (lane >> BIT) & 1;
#pragma unroll
    for (int j = 0; j < HALF; ++j) {
        float send = hi ? acc[j] : acc[j + HALF];
        float recv = __shfl_xor(send, MASK, 64);
        float keep = hi ? acc[j + HALF] : acc[j];
        acc[j] = keep + recv;
    }
}

__global__ __launch_bounds__(256) void ani_kernel(
    const float* __restrict__ coords, const int* __restrict__ atom_types,
    const float* __restrict__ EtaR, const float* __restrict__ ShfR,
    const float* __restrict__ Zeta, const float* __restrict__ ShfZ,
    const float* __restrict__ EtaA, const float* __restrict__ ShfA,
    float* __restrict__ out)
{
    __shared__ float sc[CN][3];                 // molecule coords
    __shared__ float sD [CN*LDM];               // d(j,k)
    __shared__ float sI [CN*LDM];               // 1/d(j,k)
    __shared__ float sFA[CN*LDM];               // angular cutoff f(d; 3.5)
    __shared__ float sFR[CN*LDM];               // radial  cutoff f(d; 5.2)

    const int tid  = threadIdx.x;
    const int wv   = tid >> 6;
    const int lane = tid & 63;
    const int m    = blockIdx.x / 6;            // molecule
    const int h    = blockIdx.x - m * 6;        // which sextet of centers

    // ---- stage molecule coords into LDS ----
    if (tid < CN * 3) sc[tid / 3][tid % 3] = coords[m * CN * 3 + tid];
    __syncthreads();

    // ---- 24x24 geometry, once per block ----
    for (int p = tid; p < CN * CN; p += 256) {
        const int j = p / CN, k = p - j * CN;
        const float dx = sc[j][0] - sc[k][0];
        const float dy = sc[j][1] - sc[k][1];
        const float dz = sc[j][2] - sc[k][2];
        const float d  = __builtin_amdgcn_sqrtf(dx*dx + dy*dy + dz*dz);
        const int o = j * LDM + k;
        sD [o] = d;
        sI [o] = __builtin_amdgcn_rcpf(d);      // inf on diagonal, never used
        sFA[o] = 0.5f * (__cosf(d * (float)(3.14159265358979323846/3.5)) + 1.0f);
        sFR[o] = 0.5f * (__cosf(d * (float)(3.14159265358979323846/5.2)) + 1.0f);
    }
    __syncthreads();

    // ---- this wave's single center ----
    const int i   = h * 4 + wv;                 // center atom
    const int row = m * CN + i;
    const int t   = atom_types[i];
    const int i25 = i * LDM;

    // ---- radial G2: k = lane%16, 4 neighbor groups, shuffle reduce ----
    {
        const int k = lane & 15, g = lane >> 4;
        const float eta = EtaR[t*CKR + k] * LOG2E;
        const float shf = ShfR[t*CKR + k];
        float acc = 0.0f;
        for (int n = g; n < NN; n += 4) {
            const int j = n + (n >= i ? 1 : 0);
            const float x = sD[i25 + j] - shf;
            acc += __builtin_amdgcn_exp2f(-eta * x * x) * sFR[i25 + j];
        }
        acc += __shfl_xor(acc, 16, 64);
        acc += __shfl_xor(acc, 32, 64);
        if (lane < CKR) out[row * KOUT + k] = acc;
    }

    // ---- Phase A: per-pair scalars via law of cosines (registers) ----
    float4 pd[4];
    #pragma unroll
    for (int it = 0; it < 4; ++it) {
        const int p  = lane + it * 64;
        const int n1 = cPairs.pa[p], n2 = cPairs.pb[p];
        const int j  = n1 + (n1 >= i ? 1 : 0);
        const int k2 = n2 + (n2 >= i ? 1 : 0);
        const float d12 = sD[i25 + j],  d13 = sD[i25 + k2];
        const float djk = sD[j * LDM + k2];
        const float i12 = sI[i25 + j],  i13 = sI[i25 + k2];
        float cosv = (d12*d12 + d13*d13 - djk*djk) * (0.5f * i12 * i13);
        cosv = fminf(fmaxf(cosv, -1.0f + 1e-7f), 1.0f - 1e-7f); // also scrubs NaN
        const float sinv = __builtin_amdgcn_sqrtf(1.0f - cosv * cosv);
        const float avg  = 0.5f * (d12 + d13);
        const float ff2  = (p < NP) ? 2.0f * sFA[i25 + j] * sFA[i25 + k2] : 0.0f;
        pd[it] = make_float4(cosv, sinv, avg, ff2);
    }

    // ---- structure check for the factorized fast path (wave-uniform) ----
    const float* __restrict__ Zt = ShfZ + t*CKA;
    const float* __restrict__ At = ShfA + t*CKA;
    const int kk = lane & 31;
    const bool okl = (Zeta[t*CKA + kk] == 32.0f)
                  && (EtaA[t*CKA + kk] == EtaA[t*CKA])
                  && (Zt[kk] == Zt[kk & 7])
                  && (At[kk] == At[kk & 24]);
    const bool fast = __all(okl);

    if (fast) {
        const float cgau = -EtaA[t*CKA] * LOG2E;
        float Zv[8], cAv[4], sAv[4];
        #pragma unroll
        for (int z = 0; z < 8; ++z) Zv[z] = Zt[z];
        #pragma unroll
        for (int a = 0; a < 4; ++a) {
            const float sh = At[a * 8];
            cAv[a] = __cosf(sh); sAv[a] = __sinf(sh);
        }
        float acc[32];
        #pragma unroll
        for (int k = 0; k < 32; ++k) acc[k] = 0.0f;

        #pragma unroll
        for (int it = 0; it < 4; ++it) {
            const float4 q = pd[it];
            float G[8];
            #pragma unroll
            for (int z = 0; z < 8; ++z) {
                const float x = q.z - Zv[z];
                G[z] = __builtin_amdgcn_exp2f(cgau * x * x);
            }
            #pragma unroll
            for (int a = 0; a < 4; ++a) {
                const float cosang = q.x * cAv[a] + q.y * sAv[a];
                const float hh  = 0.5f * cosang + 0.5f;      // in [0,1]
                const float h2 = hh*hh, h4 = h2*h2, h8 = h4*h4, h16 = h8*h8;
                const float Pa = (h16 * h16) * q.w;          // 2*ff*h^32
                #pragma unroll
                for (int z = 0; z < 8; ++z)
                    acc[a*8 + z] = fmaf(Pa, G[z], acc[a*8 + z]);
            }
        }

        red_level<1, 0, 16>(acc, lane);
        red_level<2, 1,  8>(acc, lane);
        red_level<4, 2,  4>(acc, lane);
        red_level<8, 3,  2>(acc, lane);
        red_level<16, 4, 1>(acc, lane);
        acc[0] += __shfl_xor(acc[0], 32, 64);
        if (lane < 32) {
            const int k = ((lane & 1) << 4) | ((lane & 2) << 2) | (lane & 4)
                        | ((lane & 8) >> 2) | ((lane & 16) >> 4);
            out[row * KOUT + CKR + k] = acc[0];
        }
    } else {
        // ---- generic fallback: k = lane%32, half-waves split pairs ----
        const int k = lane & 31, hh2 = lane >> 5;
        const float zeta  = Zeta[t*CKA + k];
        const float shfZ  = Zt[k];
        const float etaAl = EtaA[t*CKA + k] * LOG2E;
        const float shfA  = At[k];
        const float cA = __cosf(shfA), sA = __sinf(shfA);
        float acc = 0.0f;
        for (int p = hh2; p < NP; p += 2) {
            const int n1 = cPairs.pa[p], n2 = cPairs.pb[p];
            const int j  = n1 + (n1 >= i ? 1 : 0);
            const int k2 = n2 + (n2 >= i ? 1 : 0);
            const float d12 = sD[i25 + j],  d13 = sD[i25 + k2];
            const float djk = sD[j * LDM + k2];
            const float i12 = sI[i25 + j],  i13 = sI[i25 + k2];
            float cosv = (d12*d12 + d13*d13 - djk*djk) * (0.5f * i12 * i13);
            cosv = fminf(fmaxf(cosv, -1.0f + 1e-7f), 1.0f - 1e-7f);
            const float sinv = __builtin_amdgcn_sqrtf(1.0f - cosv * cosv);
            const float cosang = cosv * cA + sinv * sA;
            const float hhp = 0.5f * cosang + 0.5f;
            const float l2h = __log2f(hhp);
            const float x   = 0.5f * (d12 + d13) - shfZ;
            const float e   = zeta * l2h - etaAl * x * x;
            acc += (2.0f * sFA[i25 + j] * sFA[i25 + k2]) * __builtin_amdgcn_exp2f(e);
        }
        acc += __shfl_xor(acc, 32, 64);
        if (lane < CKA) out[row * KOUT + CKR + k] = acc;
    }
}

extern "C" void kernel_launch(void* const* d_in, const int* in_sizes, int n_in,
                              void* d_out, int out_size, void* d_ws, size_t ws_size,
                              hipStream_t stream) {
    const float* coords     = (const float*)d_in[0];
    const int*   atom_types = (const int*)  d_in[1];
    const float* EtaR       = (const float*)d_in[2];
    const float* ShfR       = (const float*)d_in[3];
    const float* Zeta       = (const float*)d_in[4];
    const float* ShfZ       = (const float*)d_in[5];
    const float* EtaA       = (const float*)d_in[6];
    const float* ShfA       = (const float*)d_in[7];
    float* out = (float*)d_out;

    dim3 grid(CB * 6), block(256);   // 6 blocks per molecule, 1 center per wave
    hipLaunchKernelGGL(ani_kernel, grid, block, 0, stream,
                       coords, atom_types, EtaR, ShfR, Zeta, ShfZ, EtaA, ShfA, out);
}